// Round 3
// baseline (473.612 us; speedup 1.0000x reference)
//
#include <hip/hip_runtime.h>

#define NCOLS 128

// ===================== fallback: per-nnz atomic scatter =====================
__global__ void __launch_bounds__(256)
spmm_atomic_kernel(const int* __restrict__ rows,
                   const int* __restrict__ cols,
                   const float* __restrict__ vals,
                   const float* __restrict__ dense,
                   float* __restrict__ out,
                   int nnz) {
    long long tid = (long long)blockIdx.x * blockDim.x + threadIdx.x;
    int i = (int)(tid >> 5);
    int chunk = (int)(tid & 31);
    if (i >= nnz) return;
    int r = rows[i];
    int c = cols[i];
    float v = vals[i];
    const float4 d =
        reinterpret_cast<const float4*>(dense + (size_t)c * NCOLS)[chunk];
    float* o = out + (size_t)r * NCOLS + (size_t)chunk * 4;
    atomicAdd(o + 0, v * d.x);
    atomicAdd(o + 1, v * d.y);
    atomicAdd(o + 2, v * d.z);
    atomicAdd(o + 3, v * d.w);
}

// ===================== CSR build =====================
__global__ void __launch_bounds__(256)
hist_kernel(const int* __restrict__ rows, int* __restrict__ counts, int nnz) {
    int i = blockIdx.x * 256 + threadIdx.x;
    if (i < nnz) atomicAdd(&counts[rows[i]], 1);
}

// per-block (1024 rows) total counts -> bsums[b]
__global__ void __launch_bounds__(256)
block_reduce_kernel(const int* __restrict__ counts, int* __restrict__ bsums,
                    int M) {
    __shared__ int lds[256];
    int b = blockIdx.x, t = threadIdx.x;
    int base = b * 1024 + t * 4;
    int s = 0;
#pragma unroll
    for (int j = 0; j < 4; ++j)
        if (base + j < M) s += counts[base + j];
    lds[t] = s;
    __syncthreads();
    for (int off = 128; off > 0; off >>= 1) {
        if (t < off) lds[t] += lds[t + off];
        __syncthreads();
    }
    if (t == 0) bsums[b] = lds[0];
}

// exclusive scan of up to 1024 block sums, in place (single block)
__global__ void __launch_bounds__(1024)
scan_bsums_kernel(int* __restrict__ bsums, int NB) {
    __shared__ int lds[1024];
    int t = threadIdx.x;
    int x = (t < NB) ? bsums[t] : 0;
    lds[t] = x;
    __syncthreads();
    for (int off = 1; off < 1024; off <<= 1) {
        int v = (t >= off) ? lds[t - off] : 0;
        __syncthreads();
        lds[t] += v;
        __syncthreads();
    }
    if (t < NB) bsums[t] = lds[t] - x;  // exclusive
}

// per-block local exclusive scan + block offset -> row_start & cursor
__global__ void __launch_bounds__(256)
offsets_kernel(const int* __restrict__ counts, const int* __restrict__ bsums,
               int* __restrict__ row_start, int* __restrict__ cursor,
               int M, int nnz) {
    __shared__ int lds[256];
    int b = blockIdx.x, t = threadIdx.x;
    int base = b * 1024 + t * 4;
    int c0 = 0, c1 = 0, c2 = 0, c3 = 0;
    if (base + 0 < M) c0 = counts[base + 0];
    if (base + 1 < M) c1 = counts[base + 1];
    if (base + 2 < M) c2 = counts[base + 2];
    if (base + 3 < M) c3 = counts[base + 3];
    int s = c0 + c1 + c2 + c3;
    lds[t] = s;
    __syncthreads();
    for (int off = 1; off < 256; off <<= 1) {
        int v = (t >= off) ? lds[t - off] : 0;
        __syncthreads();
        lds[t] += v;
        __syncthreads();
    }
    int off0 = bsums[b] + lds[t] - s;  // exclusive prefix for this thread
    int e0 = off0;
    int e1 = off0 + c0;
    int e2 = e1 + c1;
    int e3 = e2 + c2;
    if (base + 0 < M) { row_start[base + 0] = e0; cursor[base + 0] = e0; }
    if (base + 1 < M) { row_start[base + 1] = e1; cursor[base + 1] = e1; }
    if (base + 2 < M) { row_start[base + 2] = e2; cursor[base + 2] = e2; }
    if (base + 3 < M) { row_start[base + 3] = e3; cursor[base + 3] = e3; }
    if (b == 0 && t == 0) row_start[M] = nnz;
}

// scatter nnz into row-sorted packed (col, val_bits) pairs
__global__ void __launch_bounds__(256)
scatter_kernel(const int* __restrict__ rows, const int* __restrict__ cols,
               const float* __restrict__ vals, int* __restrict__ cursor,
               int2* __restrict__ spair, int nnz) {
    int i = blockIdx.x * 256 + threadIdx.x;
    if (i >= nnz) return;
    int r = rows[i];
    int pos = atomicAdd(&cursor[r], 1);
    spair[pos] = make_int2(cols[i], __float_as_int(vals[i]));
}

// ===================== CSR SpMM: one wave64 per output row =====================
// lane = p*16 + ch: p in 0..3 selects which of 4 in-flight nnz, ch in 0..15
// selects the column chunk; each lane covers 8 cols (2x float4: ch and ch+16).
// (col,val) prefetched one iteration ahead as a packed int2.
__global__ void __launch_bounds__(256)
csr_spmm_kernel(const int* __restrict__ row_start,
                const int2* __restrict__ spair,
                const float* __restrict__ dense,
                float* __restrict__ out, int M) {
    int wid = threadIdx.x >> 6;            // 4 waves per block
    int lane = threadIdx.x & 63;
    int row = blockIdx.x * 4 + wid;
    if (row >= M) return;

    int start = row_start[row];
    int end = row_start[row + 1];
    int p = lane >> 4;                     // 0..3
    int ch = lane & 15;                    // 0..15

    float4 acc0 = make_float4(0.f, 0.f, 0.f, 0.f);
    float4 acc1 = make_float4(0.f, 0.f, 0.f, 0.f);

    int kk = start + p;
    int c = 0;
    float v = 0.f;
    if (kk < end) {
        int2 t = spair[kk];
        c = t.x;
        v = __int_as_float(t.y);
    }

    for (int k = start; k < end; k += 4) {
        int kn = k + 4 + p;
        int cn = 0;
        float vn = 0.f;
        if (kn < end) {
            int2 t = spair[kn];
            cn = t.x;
            vn = __int_as_float(t.y);
        }
        const float4* drow =
            reinterpret_cast<const float4*>(dense) + (size_t)c * (NCOLS / 4);
        float4 d0 = drow[ch];
        float4 d1 = drow[ch + 16];
        acc0.x += v * d0.x;
        acc0.y += v * d0.y;
        acc0.z += v * d0.z;
        acc0.w += v * d0.w;
        acc1.x += v * d1.x;
        acc1.y += v * d1.y;
        acc1.z += v * d1.z;
        acc1.w += v * d1.w;
        c = cn;
        v = vn;
    }

    // reduce across the 4 p-groups (lane xor 16, then xor 32)
#pragma unroll
    for (int off = 16; off <= 32; off <<= 1) {
        acc0.x += __shfl_xor(acc0.x, off, 64);
        acc0.y += __shfl_xor(acc0.y, off, 64);
        acc0.z += __shfl_xor(acc0.z, off, 64);
        acc0.w += __shfl_xor(acc0.w, off, 64);
        acc1.x += __shfl_xor(acc1.x, off, 64);
        acc1.y += __shfl_xor(acc1.y, off, 64);
        acc1.z += __shfl_xor(acc1.z, off, 64);
        acc1.w += __shfl_xor(acc1.w, off, 64);
    }

    if (p == 0) {
        float4* orow = reinterpret_cast<float4*>(out) + (size_t)row * (NCOLS / 4);
        orow[ch] = acc0;
        orow[ch + 16] = acc1;
    }
}

// ===================== host =====================
extern "C" void kernel_launch(void* const* d_in, const int* in_sizes, int n_in,
                              void* d_out, int out_size, void* d_ws, size_t ws_size,
                              hipStream_t stream) {
    const int*   idx   = (const int*)d_in[0];    // [2, NNZ]: rows then cols
    const float* vals  = (const float*)d_in[1];  // [NNZ]
    const float* dense = (const float*)d_in[2];  // [K, 128]
    float*       out   = (float*)d_out;          // [M, 128]

    const int nnz = in_sizes[1];
    const int* rows = idx;
    const int* cols = idx + nnz;
    const int M = out_size / NCOLS;
    const int NB = (M + 1023) / 1024;

    // workspace layout (int units); spair first for 8B alignment
    size_t o_spair  = 0;
    size_t o_counts = o_spair + 2 * (size_t)nnz;
    size_t o_cursor = o_counts + (size_t)M;
    size_t o_rs     = o_cursor + (size_t)M;
    size_t o_bsums  = o_rs + (size_t)(M + 1);
    size_t need_bytes = (o_bsums + (size_t)NB) * 4;

    if (need_bytes <= ws_size && NB <= 1024) {
        int* wsI = (int*)d_ws;
        int2*  spair     = (int2*)(wsI + o_spair);
        int*   counts    = wsI + o_counts;
        int*   cursor    = wsI + o_cursor;
        int*   row_start = wsI + o_rs;
        int*   bsums     = wsI + o_bsums;

        hipMemsetAsync(counts, 0, (size_t)M * 4, stream);
        hist_kernel<<<(nnz + 255) / 256, 256, 0, stream>>>(rows, counts, nnz);
        block_reduce_kernel<<<NB, 256, 0, stream>>>(counts, bsums, M);
        scan_bsums_kernel<<<1, 1024, 0, stream>>>(bsums, NB);
        offsets_kernel<<<NB, 256, 0, stream>>>(counts, bsums, row_start, cursor,
                                               M, nnz);
        scatter_kernel<<<(nnz + 255) / 256, 256, 0, stream>>>(rows, cols, vals,
                                                              cursor, spair, nnz);
        csr_spmm_kernel<<<(M + 3) / 4, 256, 0, stream>>>(row_start, spair,
                                                         dense, out, M);
    } else {
        // fallback: atomic scatter
        hipMemsetAsync(d_out, 0, (size_t)out_size * sizeof(float), stream);
        const long long total = (long long)nnz * 32;
        spmm_atomic_kernel<<<(int)((total + 255) / 256), 256, 0, stream>>>(
            rows, cols, vals, dense, out, nnz);
    }
}

// Round 4
// 310.010 us; speedup vs baseline: 1.5277x; 1.5277x over previous
//
#include <hip/hip_runtime.h>

#define NCOLS 128
#define BROWS 128            // rows per bucket
#define CAP   3072           // element capacity per bucket (mean 2560 + 10 sigma)
#define TILE  8192           // elements per bin tile (256 thr x 32)
#define OVCAP 65536

// ===================== new path: bucket bin + in-bucket sort =====================

// Tile-binning: LDS histogram -> per-bucket global reservation -> packed write.
__global__ void __launch_bounds__(256)
bin_kernel(const int* __restrict__ rows, const int* __restrict__ cols,
           const float* __restrict__ vals, int nnz, int nbuck,
           int2* __restrict__ scratch, int* __restrict__ bcur,
           int3* __restrict__ ovlist, int* __restrict__ ovcur) {
    __shared__ int cnt[800];
    __shared__ int gbase[800];
    int tid = threadIdx.x;
    int tile_base = blockIdx.x * TILE;

    for (int i = tid; i < nbuck; i += 256) cnt[i] = 0;
    __syncthreads();

    int myrow[32];
#pragma unroll
    for (int j = 0; j < 32; ++j) {
        int idx = tile_base + j * 256 + tid;
        int r = (idx < nnz) ? rows[idx] : -1;
        myrow[j] = r;
        if (r >= 0) atomicAdd(&cnt[r >> 7], 1);
    }
    __syncthreads();

    for (int b = tid; b < nbuck; b += 256) {
        int c = cnt[b];
        gbase[b] = (c > 0) ? atomicAdd(&bcur[b], c) : 0;
    }
    __syncthreads();
    for (int i = tid; i < nbuck; i += 256) cnt[i] = 0;  // reuse as rank cursor
    __syncthreads();

#pragma unroll
    for (int j = 0; j < 32; ++j) {
        int idx = tile_base + j * 256 + tid;
        int r = myrow[j];
        if (r < 0) continue;
        int b = r >> 7;
        int rank = atomicAdd(&cnt[b], 1);
        int pos = gbase[b] + rank;
        int c = cols[idx];
        int vbits = __float_as_int(vals[idx]);
        if (pos < CAP) {
            scratch[(size_t)b * CAP + pos] = make_int2(((r & 127) << 17) | c, vbits);
        } else {
            int o = atomicAdd(ovcur, 1);
            if (o < OVCAP) ovlist[o] = make_int3(r, c, vbits);
        }
    }
}

// One block per bucket: LDS-stage, histogram by local row, scan, place in-place.
// Emits row_start/row_end pointing into the gapped bucket-major scratch.
__global__ void __launch_bounds__(256)
sort_bucket_kernel(int2* __restrict__ scratch, const int* __restrict__ bcur,
                   int* __restrict__ row_start, int* __restrict__ row_end,
                   int M) {
    __shared__ int2 stage[CAP];
    __shared__ int cnt[BROWS];
    __shared__ int off[BROWS];
    int b = blockIdx.x;
    int tid = threadIdx.x;
    int n = bcur[b];
    if (n > CAP) n = CAP;
    size_t base = (size_t)b * CAP;

    for (int i = tid; i < n; i += 256) stage[i] = scratch[base + i];
    if (tid < BROWS) cnt[tid] = 0;
    __syncthreads();

    for (int i = tid; i < n; i += 256) atomicAdd(&cnt[stage[i].x >> 17], 1);
    __syncthreads();

    // inclusive Hillis-Steele scan of cnt -> off
    if (tid < BROWS) off[tid] = cnt[tid];
    __syncthreads();
    for (int s = 1; s < BROWS; s <<= 1) {
        int v = 0;
        if (tid < BROWS && tid >= s) v = off[tid - s];
        __syncthreads();
        if (tid < BROWS) off[tid] += v;
        __syncthreads();
    }

    if (tid < BROWS) {
        int r = b * BROWS + tid;
        int excl = off[tid] - cnt[tid];
        if (r < M) {
            row_start[r] = (int)(base + excl);
            row_end[r]   = (int)(base + off[tid]);
        }
        off[tid] = excl;  // reuse as placement cursor
    }
    __syncthreads();

    for (int i = tid; i < n; i += 256) {
        int lr = stage[i].x >> 17;
        int p = atomicAdd(&off[lr], 1);
        scratch[base + p] = stage[i];
    }
}

// Handle (astronomically rare) bucket-capacity overflow via atomics, after spmm.
__global__ void __launch_bounds__(256)
overflow_kernel(const int3* __restrict__ ovlist, const int* __restrict__ ovcur,
                const float* __restrict__ dense, float* __restrict__ out) {
    int n = *ovcur;
    if (n > OVCAP) n = OVCAP;
    int tid = blockIdx.x * blockDim.x + threadIdx.x;
    int nth = gridDim.x * blockDim.x;
    for (int e = tid >> 5; e < n; e += nth >> 5) {
        int3 t = ovlist[e];
        float v = __int_as_float(t.z);
        int chunk = tid & 31;
        const float4 d =
            reinterpret_cast<const float4*>(dense + (size_t)t.y * NCOLS)[chunk];
        float* o = out + (size_t)t.x * NCOLS + chunk * 4;
        atomicAdd(o + 0, v * d.x);
        atomicAdd(o + 1, v * d.y);
        atomicAdd(o + 2, v * d.z);
        atomicAdd(o + 3, v * d.w);
    }
}

// CSR SpMM: one wave64 per row, 4 nnz in flight (p = lane>>4), 16 lanes x 8 cols.
__global__ void __launch_bounds__(256)
csr_spmm_kernel(const int* __restrict__ row_start, const int* __restrict__ row_end,
                const int2* __restrict__ spair, const float* __restrict__ dense,
                float* __restrict__ out, int M) {
    int wid = threadIdx.x >> 6;
    int lane = threadIdx.x & 63;
    int row = blockIdx.x * 4 + wid;
    if (row >= M) return;

    int start = row_start[row];
    int end = row_end[row];
    int p = lane >> 4;
    int ch = lane & 15;

    float4 acc0 = make_float4(0.f, 0.f, 0.f, 0.f);
    float4 acc1 = make_float4(0.f, 0.f, 0.f, 0.f);

    int kk = start + p;
    int c = 0;
    float v = 0.f;
    if (kk < end) {
        int2 t = spair[kk];
        c = t.x & 0x1FFFF;
        v = __int_as_float(t.y);
    }

    for (int k = start; k < end; k += 4) {
        int kn = k + 4 + p;
        int cn = 0;
        float vn = 0.f;
        if (kn < end) {
            int2 t = spair[kn];
            cn = t.x & 0x1FFFF;
            vn = __int_as_float(t.y);
        }
        const float4* drow =
            reinterpret_cast<const float4*>(dense) + (size_t)c * (NCOLS / 4);
        float4 d0 = drow[ch];
        float4 d1 = drow[ch + 16];
        acc0.x += v * d0.x;
        acc0.y += v * d0.y;
        acc0.z += v * d0.z;
        acc0.w += v * d0.w;
        acc1.x += v * d1.x;
        acc1.y += v * d1.y;
        acc1.z += v * d1.z;
        acc1.w += v * d1.w;
        c = cn;
        v = vn;
    }

#pragma unroll
    for (int off = 16; off <= 32; off <<= 1) {
        acc0.x += __shfl_xor(acc0.x, off, 64);
        acc0.y += __shfl_xor(acc0.y, off, 64);
        acc0.z += __shfl_xor(acc0.z, off, 64);
        acc0.w += __shfl_xor(acc0.w, off, 64);
        acc1.x += __shfl_xor(acc1.x, off, 64);
        acc1.y += __shfl_xor(acc1.y, off, 64);
        acc1.z += __shfl_xor(acc1.z, off, 64);
        acc1.w += __shfl_xor(acc1.w, off, 64);
    }

    if (p == 0) {
        float4* orow = reinterpret_cast<float4*>(out) + (size_t)row * (NCOLS / 4);
        orow[ch] = acc0;
        orow[ch + 16] = acc1;
    }
}

// ===================== fallback level 2: previous proven CSR path =====================
__global__ void __launch_bounds__(256)
hist_kernel(const int* __restrict__ rows, int* __restrict__ counts, int nnz) {
    int i = blockIdx.x * 256 + threadIdx.x;
    if (i < nnz) atomicAdd(&counts[rows[i]], 1);
}

__global__ void __launch_bounds__(256)
block_reduce_kernel(const int* __restrict__ counts, int* __restrict__ bsums,
                    int M) {
    __shared__ int lds[256];
    int b = blockIdx.x, t = threadIdx.x;
    int base = b * 1024 + t * 4;
    int s = 0;
#pragma unroll
    for (int j = 0; j < 4; ++j)
        if (base + j < M) s += counts[base + j];
    lds[t] = s;
    __syncthreads();
    for (int off = 128; off > 0; off >>= 1) {
        if (t < off) lds[t] += lds[t + off];
        __syncthreads();
    }
    if (t == 0) bsums[b] = lds[0];
}

__global__ void __launch_bounds__(1024)
scan_bsums_kernel(int* __restrict__ bsums, int NB) {
    __shared__ int lds[1024];
    int t = threadIdx.x;
    int x = (t < NB) ? bsums[t] : 0;
    lds[t] = x;
    __syncthreads();
    for (int off = 1; off < 1024; off <<= 1) {
        int v = (t >= off) ? lds[t - off] : 0;
        __syncthreads();
        lds[t] += v;
        __syncthreads();
    }
    if (t < NB) bsums[t] = lds[t] - x;
}

__global__ void __launch_bounds__(256)
offsets_kernel(const int* __restrict__ counts, const int* __restrict__ bsums,
               int* __restrict__ row_start, int* __restrict__ row_endx,
               int* __restrict__ cursor, int M, int nnz) {
    __shared__ int lds[256];
    int b = blockIdx.x, t = threadIdx.x;
    int base = b * 1024 + t * 4;
    int c0 = 0, c1 = 0, c2 = 0, c3 = 0;
    if (base + 0 < M) c0 = counts[base + 0];
    if (base + 1 < M) c1 = counts[base + 1];
    if (base + 2 < M) c2 = counts[base + 2];
    if (base + 3 < M) c3 = counts[base + 3];
    int s = c0 + c1 + c2 + c3;
    lds[t] = s;
    __syncthreads();
    for (int off = 1; off < 256; off <<= 1) {
        int v = (t >= off) ? lds[t - off] : 0;
        __syncthreads();
        lds[t] += v;
        __syncthreads();
    }
    int off0 = bsums[b] + lds[t] - s;
    int e0 = off0, e1 = off0 + c0, e2 = e1 + c1, e3 = e2 + c2;
    if (base + 0 < M) { row_start[base + 0] = e0; row_endx[base + 0] = e1; cursor[base + 0] = e0; }
    if (base + 1 < M) { row_start[base + 1] = e1; row_endx[base + 1] = e2; cursor[base + 1] = e1; }
    if (base + 2 < M) { row_start[base + 2] = e2; row_endx[base + 2] = e3; cursor[base + 2] = e2; }
    if (base + 3 < M) { row_start[base + 3] = e3; row_endx[base + 3] = e3 + c3; cursor[base + 3] = e3; }
}

__global__ void __launch_bounds__(256)
scatter_kernel(const int* __restrict__ rows, const int* __restrict__ cols,
               const float* __restrict__ vals, int* __restrict__ cursor,
               int2* __restrict__ spair, int nnz) {
    int i = blockIdx.x * 256 + threadIdx.x;
    if (i >= nnz) return;
    int r = rows[i];
    int pos = atomicAdd(&cursor[r], 1);
    spair[pos] = make_int2(cols[i] & 0x1FFFF, __float_as_int(vals[i]));
}

// ===================== fallback level 3: atomic =====================
__global__ void __launch_bounds__(256)
spmm_atomic_kernel(const int* __restrict__ rows, const int* __restrict__ cols,
                   const float* __restrict__ vals, const float* __restrict__ dense,
                   float* __restrict__ out, int nnz) {
    long long tid = (long long)blockIdx.x * blockDim.x + threadIdx.x;
    int i = (int)(tid >> 5);
    int chunk = (int)(tid & 31);
    if (i >= nnz) return;
    int r = rows[i];
    int c = cols[i];
    float v = vals[i];
    const float4 d =
        reinterpret_cast<const float4*>(dense + (size_t)c * NCOLS)[chunk];
    float* o = out + (size_t)r * NCOLS + (size_t)chunk * 4;
    atomicAdd(o + 0, v * d.x);
    atomicAdd(o + 1, v * d.y);
    atomicAdd(o + 2, v * d.z);
    atomicAdd(o + 3, v * d.w);
}

// ===================== host =====================
extern "C" void kernel_launch(void* const* d_in, const int* in_sizes, int n_in,
                              void* d_out, int out_size, void* d_ws, size_t ws_size,
                              hipStream_t stream) {
    const int*   idx   = (const int*)d_in[0];
    const float* vals  = (const float*)d_in[1];
    const float* dense = (const float*)d_in[2];
    float*       out   = (float*)d_out;

    const int nnz = in_sizes[1];
    const int* rows = idx;
    const int* cols = idx + nnz;
    const int M = out_size / NCOLS;
    const int nbuck = (M + BROWS - 1) / BROWS;

    // ---- new-path workspace layout (bytes, 8B-aligned blocks first) ----
    size_t o_scratch = 0;                                  // int2 [nbuck*CAP]
    size_t o_ovlist  = o_scratch + (size_t)nbuck * CAP * 8;  // int3 [OVCAP]
    size_t o_bcur    = o_ovlist + (size_t)OVCAP * 12;        // int [nbuck]
    size_t o_ovcur   = o_bcur + (size_t)nbuck * 4;           // int
    size_t o_rs      = o_ovcur + 4;                          // int [M]
    size_t o_re      = o_rs + (size_t)M * 4;                 // int [M]
    size_t need_new  = o_re + (size_t)M * 4;

    if (need_new <= ws_size && nbuck <= 800) {
        char* ws = (char*)d_ws;
        int2* scratch   = (int2*)(ws + o_scratch);
        int3* ovlist    = (int3*)(ws + o_ovlist);
        int*  bcur      = (int*)(ws + o_bcur);
        int*  ovcur     = (int*)(ws + o_ovcur);
        int*  row_start = (int*)(ws + o_rs);
        int*  row_end   = (int*)(ws + o_re);

        hipMemsetAsync(bcur, 0, (size_t)(nbuck + 1) * 4, stream);  // bcur + ovcur
        int ntile = (nnz + TILE - 1) / TILE;
        bin_kernel<<<ntile, 256, 0, stream>>>(rows, cols, vals, nnz, nbuck,
                                              scratch, bcur, ovlist, ovcur);
        sort_bucket_kernel<<<nbuck, 256, 0, stream>>>(scratch, bcur, row_start,
                                                      row_end, M);
        csr_spmm_kernel<<<(M + 3) / 4, 256, 0, stream>>>(row_start, row_end,
                                                         scratch, dense, out, M);
        overflow_kernel<<<32, 256, 0, stream>>>(ovlist, ovcur, dense, out);
        return;
    }

    // ---- fallback level 2: previous proven CSR path ----
    const int NB = (M + 1023) / 1024;
    size_t f_spair  = 0;
    size_t f_counts = f_spair + 2 * (size_t)nnz;
    size_t f_cursor = f_counts + (size_t)M;
    size_t f_rs     = f_cursor + (size_t)M;
    size_t f_re     = f_rs + (size_t)M;
    size_t f_bsums  = f_re + (size_t)M;
    size_t need_old = (f_bsums + (size_t)NB) * 4;

    if (need_old <= ws_size && NB <= 1024) {
        int* wsI = (int*)d_ws;
        int2* spair     = (int2*)(wsI + f_spair);
        int*  counts    = wsI + f_counts;
        int*  cursor    = wsI + f_cursor;
        int*  row_start = wsI + f_rs;
        int*  row_end   = wsI + f_re;
        int*  bsums     = wsI + f_bsums;

        hipMemsetAsync(counts, 0, (size_t)M * 4, stream);
        hist_kernel<<<(nnz + 255) / 256, 256, 0, stream>>>(rows, counts, nnz);
        block_reduce_kernel<<<NB, 256, 0, stream>>>(counts, bsums, M);
        scan_bsums_kernel<<<1, 1024, 0, stream>>>(bsums, NB);
        offsets_kernel<<<NB, 256, 0, stream>>>(counts, bsums, row_start, row_end,
                                               cursor, M, nnz);
        scatter_kernel<<<(nnz + 255) / 256, 256, 0, stream>>>(rows, cols, vals,
                                                              cursor, spair, nnz);
        csr_spmm_kernel<<<(M + 3) / 4, 256, 0, stream>>>(row_start, row_end,
                                                         spair, dense, out, M);
        return;
    }

    hipMemsetAsync(d_out, 0, (size_t)out_size * sizeof(float), stream);
    const long long total = (long long)nnz * 32;
    spmm_atomic_kernel<<<(int)((total + 255) / 256), 256, 0, stream>>>(
        rows, cols, vals, dense, out, nnz);
}